// Round 1
// baseline (603.804 us; speedup 1.0000x reference)
//
#include <hip/hip_runtime.h>
#include <stdint.h>
#include <math.h>

#define T_SEQ 2048
#define HID   2880
#define QKV_D 5120   // 64*80
#define OD    4096   // 64 heads * 64
#define NQH   64
#define SM_SCALE 0.125f
#define LOG2E 1.44269504088896340736f

typedef float f32x4 __attribute__((ext_vector_type(4)));
typedef short bf16x8 __attribute__((ext_vector_type(8)));

__device__ __forceinline__ unsigned short f2bf(float f) {
  union { float f; unsigned u; } v; v.f = f;
  unsigned r = v.u + 0x7fffu + ((v.u >> 16) & 1u);
  return (unsigned short)(r >> 16);
}
__device__ __forceinline__ float bf2f(unsigned short h) {
  union { unsigned u; float f; } v; v.u = ((unsigned)h) << 16;
  return v.f;
}
__device__ __forceinline__ void gld_lds16(const void* g, void* l) {
  __builtin_amdgcn_global_load_lds(
      (const __attribute__((address_space(1))) unsigned int*)g,
      (__attribute__((address_space(3))) unsigned int*)l, 16, 0, 0);
}

// ---------------- RMSNorm: x (f32) -> t (bf16) ----------------
__global__ __launch_bounds__(256) void rmsnorm_k(const float* __restrict__ x,
                                                 const float* __restrict__ scale,
                                                 unsigned short* __restrict__ t) {
  int row = blockIdx.x;
  const float4* xr = (const float4*)(x + (size_t)row * HID); // 720 float4
  float s = 0.f;
  for (int i = threadIdx.x; i < 720; i += 256) {
    float4 a = xr[i];
    s += a.x * a.x + a.y * a.y + a.z * a.z + a.w * a.w;
  }
#pragma unroll
  for (int off = 32; off; off >>= 1) s += __shfl_down(s, off);
  __shared__ float wsum[4];
  int w = threadIdx.x >> 6, lane = threadIdx.x & 63;
  if (lane == 0) wsum[w] = s;
  __syncthreads();
  float tot = wsum[0] + wsum[1] + wsum[2] + wsum[3];
  float r = rsqrtf(tot / (float)HID + 1e-5f);
  const float4* sc4 = (const float4*)scale;
  ushort4* tr = (ushort4*)(t + (size_t)row * HID);
  for (int i = threadIdx.x; i < 720; i += 256) {
    float4 a = xr[i]; float4 b = sc4[i];
    ushort4 o;
    o.x = f2bf(a.x * r * b.x); o.y = f2bf(a.y * r * b.y);
    o.z = f2bf(a.z * r * b.z); o.w = f2bf(a.w * r * b.w);
    tr[i] = o;
  }
}

// ---------------- f32 -> bf16 convert ----------------
__global__ __launch_bounds__(256) void f2bf_k(const float* __restrict__ in,
                                              unsigned short* __restrict__ out, int n4) {
  int i = blockIdx.x * 256 + threadIdx.x;
  int stride = gridDim.x * 256;
  for (; i < n4; i += stride) {
    float4 a = ((const float4*)in)[i];
    ushort4 o;
    o.x = f2bf(a.x); o.y = f2bf(a.y); o.z = f2bf(a.z); o.w = f2bf(a.w);
    ((ushort4*)out)[i] = o;
  }
}

// ---------------- RoPE cos/sin table (YaRN-style NTK) ----------------
__global__ __launch_bounds__(256) void rope_tab_k(float* __restrict__ ct, float* __restrict__ st) {
  int idx = blockIdx.x * 256 + threadIdx.x; // T_SEQ*32
  int i = idx & 31, t = idx >> 5;
  double fi = (double)i;
  double freq = pow(150000.0, fi / 32.0);
  double lb = log(150000.0);
  double low  = 32.0 * log(4096.0 / (32.0 * 2.0 * M_PI)) / lb;
  double high = 32.0 * log(4096.0 / (1.0  * 2.0 * M_PI)) / lb;
  double interp = 1.0 / (32.0 * freq);
  double extrap = 1.0 / freq;
  double ramp = (fi - low) / (high - low);
  ramp = fmin(fmax(ramp, 0.0), 1.0);
  double mask = 1.0 - ramp;
  double invf = interp * (1.0 - mask) + extrap * mask;
  double conc = 0.1 * log(32.0) + 1.0;
  double th = (double)t * invf;
  ct[idx] = (float)(cos(th) * conc);
  st[idx] = (float)(sin(th) * conc);
}

// ---------------- RoPE apply to q,k (bf16 in-place) ----------------
__global__ __launch_bounds__(256) void rope_apply_k(unsigned short* __restrict__ qkv,
                                                    const float* __restrict__ ct,
                                                    const float* __restrict__ st) {
  int idx = blockIdx.x * 256 + threadIdx.x; // T_SEQ*72*32
  int i = idx & 31;
  int hh = (idx >> 5) % 72;
  int t = idx / (72 * 32);
  size_t base = (size_t)t * QKV_D + hh * 64 + i; // q cols 0..4095, k cols 4096..4607 == hh*64
  float x1 = bf2f(qkv[base]), x2 = bf2f(qkv[base + 32]);
  float c = ct[t * 32 + i], s = st[t * 32 + i];
  qkv[base]      = f2bf(x1 * c - x2 * s);
  qkv[base + 32] = f2bf(x2 * c + x1 * s);
}

// ---------------- GEMM: C[M][N] = A[M][K] * B[N][K]^T (+bias)(+resid) ----------------
// m97-style 128x128 tile, BK=32, 4 waves, global_load_lds(16B), XOR chunk swizzle.
template <bool FINAL>
__global__ __launch_bounds__(256) void gemm_k(const unsigned short* __restrict__ A,
                                              const unsigned short* __restrict__ B,
                                              const float* __restrict__ bias,
                                              const float* __restrict__ resid,
                                              unsigned short* __restrict__ Cb,
                                              float* __restrict__ Cf,
                                              int M, int N, int K) {
  __shared__ unsigned short As[128 * 32];
  __shared__ unsigned short Bs[128 * 32];
  int tid = threadIdx.x;
  int w = tid >> 6, lane = tid & 63;
  int g = lane >> 4, ln = lane & 15;
  int m0 = blockIdx.y * 128, n0 = blockIdx.x * 128;
  int wr = w >> 1, wc = w & 1;
  f32x4 acc[4][4];
#pragma unroll
  for (int a = 0; a < 4; a++)
#pragma unroll
    for (int b = 0; b < 4; b++) acc[a][b] = (f32x4){0.f, 0.f, 0.f, 0.f};

  int chunk0 = w * 64 + lane;
  for (int k0 = 0; k0 < K; k0 += 32) {
#pragma unroll
    for (int p = 0; p < 2; ++p) {
      int ch = p * 256 + chunk0;
      int row = ch >> 2, cc = ch & 3;
      int gch = cc ^ (row & 3);
      gld_lds16(A + (size_t)(m0 + row) * K + k0 + gch * 8, &As[(p * 256 + w * 64) * 8]);
      int rowB = n0 + row; if (rowB > N - 1) rowB = N - 1;
      gld_lds16(B + (size_t)rowB * K + k0 + gch * 8, &Bs[(p * 256 + w * 64) * 8]);
    }
    __syncthreads();
    bf16x8 af[4], bfr[4];
#pragma unroll
    for (int mi = 0; mi < 4; ++mi) {
      int rm = wr * 64 + mi * 16 + ln;
      int c = g ^ (rm & 3);
      af[mi] = *(const bf16x8*)&As[rm * 32 + c * 8];
    }
#pragma unroll
    for (int ni = 0; ni < 4; ++ni) {
      int rn = wc * 64 + ni * 16 + ln;
      int c = g ^ (rn & 3);
      bfr[ni] = *(const bf16x8*)&Bs[rn * 32 + c * 8];
    }
#pragma unroll
    for (int mi = 0; mi < 4; ++mi)
#pragma unroll
      for (int ni = 0; ni < 4; ++ni)
        acc[mi][ni] = __builtin_amdgcn_mfma_f32_16x16x32_bf16(af[mi], bfr[ni], acc[mi][ni], 0, 0, 0);
    __syncthreads();
  }
#pragma unroll
  for (int mi = 0; mi < 4; ++mi)
#pragma unroll
    for (int ni = 0; ni < 4; ++ni) {
      int colB = n0 + wc * 64 + ni * 16 + ln;
      if (colB >= N) continue;
      float bv = bias[colB];
#pragma unroll
      for (int r = 0; r < 4; ++r) {
        int rowC = m0 + wr * 64 + mi * 16 + g * 4 + r;
        float v = acc[mi][ni][r] + bv;
        if (FINAL) {
          Cf[(size_t)rowC * N + colB] = v + resid[(size_t)rowC * N + colB];
        } else {
          Cb[(size_t)rowC * N + colB] = f2bf(v);
        }
      }
    }
}

// ---------------- Flash attention, causal GQA ----------------
// grid(64 heads, 32 qtiles), 256 threads; wave w owns 16 q-rows.
__global__ __launch_bounds__(256) void attn_k(const unsigned short* __restrict__ qkv,
                                              unsigned short* __restrict__ o) {
  __shared__ unsigned short Ks[64 * 64];
  __shared__ unsigned short Vt[64 * 64];
  __shared__ unsigned short Ps[4][16 * 64];
  int h = blockIdx.x;
  int qt = blockIdx.y;
  int tid = threadIdx.x;
  int w = tid >> 6, lane = tid & 63;
  int g = lane >> 4, ln = lane & 15;
  int q0 = qt * 64 + w * 16;
  int kvh = h >> 3;
  int kcol = 4096 + kvh * 64;
  int vcol = 4608 + kvh * 64;
  bf16x8 qf[2];
#pragma unroll
  for (int c = 0; c < 2; ++c)
    qf[c] = *(const bf16x8*)(qkv + (size_t)(q0 + ln) * QKV_D + h * 64 + c * 32 + g * 8);
  f32x4 oacc[4];
#pragma unroll
  for (int i = 0; i < 4; i++) oacc[i] = (f32x4){0.f, 0.f, 0.f, 0.f};
  float m_run[4], l_run[4];
#pragma unroll
  for (int r = 0; r < 4; ++r) { m_run[r] = -1e30f; l_run[r] = 0.f; }

  for (int kt = 0; kt <= qt; ++kt) {
    int kv0 = kt * 64;
    // stage K (swizzled source -> linear LDS)
#pragma unroll
    for (int p = 0; p < 2; ++p) {
      int ch = p * 256 + w * 64 + lane;
      int row = ch >> 3, cc = ch & 7;
      int gch = cc ^ (row & 7);
      gld_lds16(qkv + (size_t)(kv0 + row) * QKV_D + kcol + gch * 8, &Ks[(p * 256 + w * 64) * 8]);
    }
    // stage V transposed with swizzle
#pragma unroll
    for (int p = 0; p < 2; ++p) {
      int idx = p * 256 + tid;
      int key = idx >> 3, d0 = (idx & 7) * 8;
      bf16x8 v = *(const bf16x8*)(qkv + (size_t)(kv0 + key) * QKV_D + vcol + d0);
#pragma unroll
      for (int j = 0; j < 8; ++j) {
        int d = d0 + j;
        Vt[d * 64 + (((key >> 3) ^ (d & 7)) << 3) + (key & 7)] = ((unsigned short*)&v)[j];
      }
    }
    __syncthreads();
    // S = Q K^T  (16 q-rows x 64 keys per wave)
    f32x4 sacc[4];
#pragma unroll
    for (int s = 0; s < 4; ++s) {
      sacc[s] = (f32x4){0.f, 0.f, 0.f, 0.f};
#pragma unroll
      for (int c = 0; c < 2; ++c) {
        int row = s * 16 + ln;
        int cch = (c * 4 + g) ^ (row & 7);
        bf16x8 kf = *(const bf16x8*)&Ks[row * 64 + cch * 8];
        sacc[s] = __builtin_amdgcn_mfma_f32_16x16x32_bf16(qf[c], kf, sacc[s], 0, 0, 0);
      }
    }
    float sv[4][4];
    bool diag = (kt == qt);
#pragma unroll
    for (int s = 0; s < 4; ++s)
#pragma unroll
      for (int r = 0; r < 4; ++r) {
        float x = sacc[s][r] * SM_SCALE;
        if (diag) {
          int key = kv0 + s * 16 + ln;
          int qrow = q0 + g * 4 + r;
          if (key > qrow) x = -1e30f;
        }
        sv[s][r] = x;
      }
#pragma unroll
    for (int r = 0; r < 4; ++r) {
      float mx = fmaxf(fmaxf(sv[0][r], sv[1][r]), fmaxf(sv[2][r], sv[3][r]));
#pragma unroll
      for (int off = 1; off < 16; off <<= 1) mx = fmaxf(mx, __shfl_xor(mx, off));
      float mnew = fmaxf(m_run[r], mx);
      float alpha = exp2f((m_run[r] - mnew) * LOG2E);
      m_run[r] = mnew;
      float sum = 0.f;
#pragma unroll
      for (int s = 0; s < 4; ++s) {
        float p = exp2f((sv[s][r] - mnew) * LOG2E);
        sv[s][r] = p;
        sum += p;
      }
#pragma unroll
      for (int off = 1; off < 16; off <<= 1) sum += __shfl_xor(sum, off);
      l_run[r] = l_run[r] * alpha + sum;
      oacc[0][r] *= alpha; oacc[1][r] *= alpha; oacc[2][r] *= alpha; oacc[3][r] *= alpha;
    }
    // P -> LDS (per-wave, swizzled)
#pragma unroll
    for (int s = 0; s < 4; ++s)
#pragma unroll
      for (int r = 0; r < 4; ++r) {
        int row = g * 4 + r, key = s * 16 + ln;
        Ps[w][row * 64 + (((key >> 3) ^ (row & 7)) << 3) + (key & 7)] = f2bf(sv[s][r]);
      }
    // O += P V
#pragma unroll
    for (int db = 0; db < 4; ++db) {
#pragma unroll
      for (int kk = 0; kk < 2; ++kk) {
        int pch = (kk * 4 + g) ^ (ln & 7);
        bf16x8 pf = *(const bf16x8*)&Ps[w][ln * 64 + pch * 8];
        int vrow = db * 16 + ln;
        int vch = (kk * 4 + g) ^ (vrow & 7);
        bf16x8 vf = *(const bf16x8*)&Vt[vrow * 64 + vch * 8];
        oacc[db] = __builtin_amdgcn_mfma_f32_16x16x32_bf16(pf, vf, oacc[db], 0, 0, 0);
      }
    }
    __syncthreads();
  }
#pragma unroll
  for (int db = 0; db < 4; ++db)
#pragma unroll
    for (int r = 0; r < 4; ++r) {
      int qrow = q0 + g * 4 + r;
      o[(size_t)qrow * OD + h * 64 + db * 16 + ln] = f2bf(oacc[db][r] / l_run[r]);
    }
}

extern "C" void kernel_launch(void* const* d_in, const int* in_sizes, int n_in,
                              void* d_out, int out_size, void* d_ws, size_t ws_size,
                              hipStream_t stream) {
  const float* x          = (const float*)d_in[0];
  const float* norm_scale = (const float*)d_in[1];
  const float* qkv_w      = (const float*)d_in[2];
  const float* qkv_b      = (const float*)d_in[3];
  const float* out_w      = (const float*)d_in[4];
  const float* out_b      = (const float*)d_in[5];
  float* out = (float*)d_out;

  char* ws = (char*)d_ws;
  size_t off = 0;
  auto alloc = [&](size_t bytes) {
    void* p = ws + off;
    off += (bytes + 255) & ~(size_t)255;
    return p;
  };
  unsigned short* t_bf = (unsigned short*)alloc((size_t)T_SEQ * HID * 2);
  unsigned short* wqkv = (unsigned short*)alloc((size_t)QKV_D * HID * 2);
  unsigned short* wout = (unsigned short*)alloc((size_t)HID * OD * 2);
  unsigned short* qkv  = (unsigned short*)alloc((size_t)T_SEQ * QKV_D * 2);
  unsigned short* obuf = (unsigned short*)alloc((size_t)T_SEQ * OD * 2);
  float* ct = (float*)alloc((size_t)T_SEQ * 32 * 4);
  float* st = (float*)alloc((size_t)T_SEQ * 32 * 4);

  rmsnorm_k<<<dim3(T_SEQ), dim3(256), 0, stream>>>(x, norm_scale, t_bf);
  f2bf_k<<<dim3(1024), dim3(256), 0, stream>>>(qkv_w, wqkv, QKV_D * HID / 4);
  f2bf_k<<<dim3(1024), dim3(256), 0, stream>>>(out_w, wout, HID * OD / 4);
  rope_tab_k<<<dim3(T_SEQ * 32 / 256), dim3(256), 0, stream>>>(ct, st);
  gemm_k<false><<<dim3(QKV_D / 128, T_SEQ / 128), dim3(256), 0, stream>>>(
      t_bf, wqkv, qkv_b, nullptr, qkv, nullptr, T_SEQ, QKV_D, HID);
  rope_apply_k<<<dim3(T_SEQ * 72 * 32 / 256), dim3(256), 0, stream>>>(qkv, ct, st);
  attn_k<<<dim3(NQH, T_SEQ / 64), dim3(256), 0, stream>>>(qkv, obuf);
  gemm_k<true><<<dim3((HID + 127) / 128, T_SEQ / 128), dim3(256), 0, stream>>>(
      obuf, wout, out_b, x, nullptr, out, T_SEQ, HID, OD);
}

// Round 3
// 455.875 us; speedup vs baseline: 1.3245x; 1.3245x over previous
//
#include <hip/hip_runtime.h>
#include <stdint.h>
#include <math.h>

#define T_SEQ 2048
#define HID   2880
#define QKV_D 5120   // 64*80
#define OD    4096   // 64 heads * 64
#define NQH   64
#define SM_SCALE 0.125f
#define LOG2E 1.44269504088896340736f
#define SSL (SM_SCALE * LOG2E)

typedef float f32x4 __attribute__((ext_vector_type(4)));
typedef float f32x16 __attribute__((ext_vector_type(16)));
typedef short bf16x8 __attribute__((ext_vector_type(8)));

__device__ __forceinline__ unsigned short f2bf(float f) {
  union { float f; unsigned u; } v; v.f = f;
  unsigned r = v.u + 0x7fffu + ((v.u >> 16) & 1u);
  return (unsigned short)(r >> 16);
}
__device__ __forceinline__ float bf2f(unsigned short h) {
  union { unsigned u; float f; } v; v.u = ((unsigned)h) << 16;
  return v.f;
}
__device__ __forceinline__ void gld_lds16(const void* g, void* l) {
  __builtin_amdgcn_global_load_lds(
      (const __attribute__((address_space(1))) unsigned int*)g,
      (__attribute__((address_space(3))) unsigned int*)l, 16, 0, 0);
}

// ---------------- RMSNorm: x (f32) -> t (bf16) ----------------
__global__ __launch_bounds__(256) void rmsnorm_k(const float* __restrict__ x,
                                                 const float* __restrict__ scale,
                                                 unsigned short* __restrict__ t) {
  int row = blockIdx.x;
  const float4* xr = (const float4*)(x + (size_t)row * HID); // 720 float4
  float s = 0.f;
  for (int i = threadIdx.x; i < 720; i += 256) {
    float4 a = xr[i];
    s += a.x * a.x + a.y * a.y + a.z * a.z + a.w * a.w;
  }
#pragma unroll
  for (int off = 32; off; off >>= 1) s += __shfl_down(s, off);
  __shared__ float wsum[4];
  int w = threadIdx.x >> 6, lane = threadIdx.x & 63;
  if (lane == 0) wsum[w] = s;
  __syncthreads();
  float tot = wsum[0] + wsum[1] + wsum[2] + wsum[3];
  float r = rsqrtf(tot / (float)HID + 1e-5f);
  const float4* sc4 = (const float4*)scale;
  ushort4* tr = (ushort4*)(t + (size_t)row * HID);
  for (int i = threadIdx.x; i < 720; i += 256) {
    float4 a = xr[i]; float4 b = sc4[i];
    ushort4 o;
    o.x = f2bf(a.x * r * b.x); o.y = f2bf(a.y * r * b.y);
    o.z = f2bf(a.z * r * b.z); o.w = f2bf(a.w * r * b.w);
    tr[i] = o;
  }
}

// ---------------- f32 -> bf16 convert ----------------
__global__ __launch_bounds__(256) void f2bf_k(const float* __restrict__ in,
                                              unsigned short* __restrict__ out, int n4) {
  int i = blockIdx.x * 256 + threadIdx.x;
  int stride = gridDim.x * 256;
  for (; i < n4; i += stride) {
    float4 a = ((const float4*)in)[i];
    ushort4 o;
    o.x = f2bf(a.x); o.y = f2bf(a.y); o.z = f2bf(a.z); o.w = f2bf(a.w);
    ((ushort4*)out)[i] = o;
  }
}

// ---------------- RoPE cos/sin table (YaRN-style NTK) ----------------
__global__ __launch_bounds__(256) void rope_tab_k(float* __restrict__ ct, float* __restrict__ st) {
  int idx = blockIdx.x * 256 + threadIdx.x; // T_SEQ*32
  int i = idx & 31, t = idx >> 5;
  double fi = (double)i;
  double freq = pow(150000.0, fi / 32.0);
  double lb = log(150000.0);
  double low  = 32.0 * log(4096.0 / (32.0 * 2.0 * M_PI)) / lb;
  double high = 32.0 * log(4096.0 / (1.0  * 2.0 * M_PI)) / lb;
  double interp = 1.0 / (32.0 * freq);
  double extrap = 1.0 / freq;
  double ramp = (fi - low) / (high - low);
  ramp = fmin(fmax(ramp, 0.0), 1.0);
  double mask = 1.0 - ramp;
  double invf = interp * (1.0 - mask) + extrap * mask;
  double conc = 0.1 * log(32.0) + 1.0;
  double th = (double)t * invf;
  ct[idx] = (float)(cos(th) * conc);
  st[idx] = (float)(sin(th) * conc);
}

// ---------------- RoPE apply to q,k (bf16 in-place) ----------------
__global__ __launch_bounds__(256) void rope_apply_k(unsigned short* __restrict__ qkv,
                                                    const float* __restrict__ ct,
                                                    const float* __restrict__ st) {
  int idx = blockIdx.x * 256 + threadIdx.x; // T_SEQ*72*32
  int i = idx & 31;
  int hh = (idx >> 5) % 72;
  int t = idx / (72 * 32);
  size_t base = (size_t)t * QKV_D + hh * 64 + i;
  float x1 = bf2f(qkv[base]), x2 = bf2f(qkv[base + 32]);
  float c = ct[t * 32 + i], s = st[t * 32 + i];
  qkv[base]      = f2bf(x1 * c - x2 * s);
  qkv[base + 32] = f2bf(x2 * c + x1 * s);
}

// ---------------- V transpose: vt[kvh][d][t] = V[t][kvh][d] ----------------
__global__ __launch_bounds__(256) void vtrans_k(const unsigned short* __restrict__ qkv,
                                                unsigned short* __restrict__ vt) {
  __shared__ unsigned short tile[64][72];
  int g = blockIdx.y;
  int t0 = blockIdx.x * 64;
  int tid = threadIdx.x;
#pragma unroll
  for (int p = 0; p < 2; ++p) {
    int ch = p * 256 + tid;
    int i = ch >> 3, j0 = (ch & 7) * 8;
    bf16x8 v = *(const bf16x8*)(qkv + (size_t)(t0 + i) * QKV_D + 4608 + g * 64 + j0);
    *(bf16x8*)&tile[i][j0] = v;
  }
  __syncthreads();
#pragma unroll
  for (int p = 0; p < 2; ++p) {
    int ch = p * 256 + tid;
    int j = ch >> 3, i0 = (ch & 7) * 8;
    union { unsigned short u[8]; bf16x8 v; } pk;
#pragma unroll
    for (int m = 0; m < 8; ++m) pk.u[m] = tile[i0 + m][j];
    *(bf16x8*)(vt + (size_t)(g * 64 + j) * T_SEQ + t0 + i0) = pk.v;
  }
}

// ---------------- GEMM: C[M][N] = A[M][K] * B[N][K]^T (+bias)(+resid) ----------------
template <bool FINAL>
__global__ __launch_bounds__(256) void gemm_k(const unsigned short* __restrict__ A,
                                              const unsigned short* __restrict__ B,
                                              const float* __restrict__ bias,
                                              const float* __restrict__ resid,
                                              unsigned short* __restrict__ Cb,
                                              float* __restrict__ Cf,
                                              int M, int N, int K) {
  __shared__ unsigned short As[128 * 32];
  __shared__ unsigned short Bs[128 * 32];
  int tid = threadIdx.x;
  int w = tid >> 6, lane = tid & 63;
  int g = lane >> 4, ln = lane & 15;
  int m0 = blockIdx.y * 128, n0 = blockIdx.x * 128;
  int wr = w >> 1, wc = w & 1;
  f32x4 acc[4][4];
#pragma unroll
  for (int a = 0; a < 4; a++)
#pragma unroll
    for (int b = 0; b < 4; b++) acc[a][b] = (f32x4){0.f, 0.f, 0.f, 0.f};

  int chunk0 = w * 64 + lane;
  for (int k0 = 0; k0 < K; k0 += 32) {
#pragma unroll
    for (int p = 0; p < 2; ++p) {
      int ch = p * 256 + chunk0;
      int row = ch >> 2, cc = ch & 3;
      int gch = cc ^ (row & 3);
      gld_lds16(A + (size_t)(m0 + row) * K + k0 + gch * 8, &As[(p * 256 + w * 64) * 8]);
      int rowB = n0 + row; if (rowB > N - 1) rowB = N - 1;
      gld_lds16(B + (size_t)rowB * K + k0 + gch * 8, &Bs[(p * 256 + w * 64) * 8]);
    }
    __syncthreads();
    bf16x8 af[4], bfr[4];
#pragma unroll
    for (int mi = 0; mi < 4; ++mi) {
      int rm = wr * 64 + mi * 16 + ln;
      int c = g ^ (rm & 3);
      af[mi] = *(const bf16x8*)&As[rm * 32 + c * 8];
    }
#pragma unroll
    for (int ni = 0; ni < 4; ++ni) {
      int rn = wc * 64 + ni * 16 + ln;
      int c = g ^ (rn & 3);
      bfr[ni] = *(const bf16x8*)&Bs[rn * 32 + c * 8];
    }
#pragma unroll
    for (int mi = 0; mi < 4; ++mi)
#pragma unroll
      for (int ni = 0; ni < 4; ++ni)
        acc[mi][ni] = __builtin_amdgcn_mfma_f32_16x16x32_bf16(af[mi], bfr[ni], acc[mi][ni], 0, 0, 0);
    __syncthreads();
  }
#pragma unroll
  for (int mi = 0; mi < 4; ++mi)
#pragma unroll
    for (int ni = 0; ni < 4; ++ni) {
      int colB = n0 + wc * 64 + ni * 16 + ln;
      if (colB >= N) continue;
      float bv = bias[colB];
#pragma unroll
      for (int r = 0; r < 4; ++r) {
        int rowC = m0 + wr * 64 + mi * 16 + g * 4 + r;
        float v = acc[mi][ni][r] + bv;
        if (FINAL) {
          Cf[(size_t)rowC * N + colB] = v + resid[(size_t)rowC * N + colB];
        } else {
          Cb[(size_t)rowC * N + colB] = f2bf(v);
        }
      }
    }
}

// ---------------- Flash attention v2b: 32x32 swapped-operand, causal GQA ----------------
// grid(64 heads, 16 qtiles reversed), 4 warps x 32 q-rows. KVBLK=64, D=64.
// P-fragment cross-half exchange via __shfl_xor(.,32) (unambiguous semantics).
__global__ __launch_bounds__(256) void attn2_k(const unsigned short* __restrict__ qkv,
                                               const unsigned short* __restrict__ vt,
                                               unsigned short* __restrict__ o) {
  __shared__ unsigned short Ks[2][64 * 64];
  __shared__ unsigned short Vs[2][64 * 64];
  int h = blockIdx.x;
  int qt = (int)gridDim.y - 1 - (int)blockIdx.y;  // long blocks first
  int tid = threadIdx.x;
  int w = tid >> 6, lane = tid & 63;
  int l31 = lane & 31, hi = lane >> 5;
  int qb0 = qt * 128;
  int q0w = qb0 + w * 32;
  int kvh = h >> 3;
  const unsigned short* kbase = qkv + 4096 + (size_t)kvh * 64;
  const unsigned short* vtb = vt + (size_t)kvh * 64 * T_SEQ;

  // Q fragments (B-operand of swapped QK^T): col q = lane&31, d = dt*16 + hi*8 + j
  bf16x8 qf[4];
  {
    const unsigned short* qrow = qkv + (size_t)(q0w + l31) * QKV_D + h * 64;
#pragma unroll
    for (int dt = 0; dt < 4; ++dt)
      qf[dt] = *(const bf16x8*)(qrow + dt * 16 + hi * 8);
  }
  f32x16 oacc[2];
#pragma unroll
  for (int r = 0; r < 16; ++r) { oacc[0][r] = 0.f; oacc[1][r] = 0.f; }
  float m_run = -1e30f, l_run = 0.f;
  int nt = qt * 2 + 2;

  auto STAGE = [&](int t, int buf) {
    int kv0 = t * 64;
#pragma unroll
    for (int p = 0; p < 2; ++p) {
      int ch = p * 256 + w * 64 + lane;
      int row = ch >> 3, cc = ch & 7;
      int gch = cc ^ (row & 7);
      gld_lds16(kbase + (size_t)(kv0 + row) * QKV_D + gch * 8, &Ks[buf][(p * 256 + w * 64) * 8]);
      gld_lds16(vtb + (size_t)row * T_SEQ + kv0 + gch * 8, &Vs[buf][(p * 256 + w * 64) * 8]);
    }
  };

  STAGE(0, 0);
  __syncthreads();
  for (int t = 0; t < nt; ++t) {
    int cur = t & 1;
    if (t + 1 < nt) STAGE(t + 1, cur ^ 1);
    int kv0 = t * 64;
    if (kv0 <= q0w + 31) {  // tile not fully masked for this warp
      const unsigned short* K_ = Ks[cur];
      const unsigned short* V_ = Vs[cur];
      // S^T = K * Q^T  (two 32-k subtiles)
      f32x16 pa[2];
#pragma unroll
      for (int kt2 = 0; kt2 < 2; ++kt2) {
        f32x16 acc;
#pragma unroll
        for (int r = 0; r < 16; ++r) acc[r] = 0.f;
        int rk = kt2 * 32 + l31;
#pragma unroll
        for (int dt = 0; dt < 4; ++dt) {
          int c = dt * 2 + hi;
          bf16x8 kf = *(const bf16x8*)&K_[rk * 64 + (c ^ (rk & 7)) * 8];
          acc = __builtin_amdgcn_mfma_f32_32x32x16_bf16(kf, qf[dt], acc, 0, 0, 0);
        }
        pa[kt2] = acc;
      }
      bool diag = (kv0 + 64 > q0w);
      int q = q0w + l31;
      float s2[32];
#pragma unroll
      for (int kt2 = 0; kt2 < 2; ++kt2)
#pragma unroll
        for (int r = 0; r < 16; ++r) {
          float x = pa[kt2][r] * SSL;
          if (diag) {
            int k = kv0 + kt2 * 32 + (r & 3) + 8 * (r >> 2) + 4 * hi;
            if (k > q) x = -3.0e38f;
          }
          s2[kt2 * 16 + r] = x;
        }
      float mx = s2[0];
#pragma unroll
      for (int i = 1; i < 32; ++i) mx = fmaxf(mx, s2[i]);
      mx = fmaxf(mx, __shfl_xor(mx, 32));
      float mnew = fmaxf(m_run, mx);
      float alpha = exp2f(m_run - mnew);
      m_run = mnew;
      float sum = 0.f;
#pragma unroll
      for (int i = 0; i < 32; ++i) {
        float p = exp2f(s2[i] - mnew);
        s2[i] = p;
        sum += p;
      }
      sum += __shfl_xor(sum, 32);
      l_run = l_run * alpha + sum;
#pragma unroll
      for (int r = 0; r < 16; ++r) { oacc[0][r] *= alpha; oacc[1][r] *= alpha; }
      // pack P -> bf16 words: pw[kt2*8+i] = pack(s2[kt2*16+2i], s2[kt2*16+2i+1])
      unsigned pw[16];
#pragma unroll
      for (int kt2 = 0; kt2 < 2; ++kt2)
#pragma unroll
        for (int i = 0; i < 8; ++i) {
          unsigned r_;
          asm("v_cvt_pk_bf16_f32 %0, %1, %2"
              : "=v"(r_) : "v"(s2[kt2 * 16 + 2 * i]), "v"(s2[kt2 * 16 + 2 * i + 1]));
          pw[kt2 * 8 + i] = r_;
        }
      // cross-half exchange -> B-fragment words bw[kt2][a][w]
      // required: w0=(hi0:self p0, hi1:partner p2) w1=(hi0:self p1, hi1:partner p3)
      //           w2=(hi0:partner p0, hi1:self p2) w3=(hi0:partner p1, hi1:self p3)
      unsigned bw[2][2][4];
#pragma unroll
      for (int kt2 = 0; kt2 < 2; ++kt2)
#pragma unroll
        for (int a = 0; a < 2; ++a) {
          unsigned p0 = pw[kt2 * 8 + a * 4 + 0];
          unsigned p1 = pw[kt2 * 8 + a * 4 + 1];
          unsigned p2 = pw[kt2 * 8 + a * 4 + 2];
          unsigned p3 = pw[kt2 * 8 + a * 4 + 3];
          unsigned e0 = (unsigned)__shfl_xor((int)p0, 32);
          unsigned e1 = (unsigned)__shfl_xor((int)p1, 32);
          unsigned e2 = (unsigned)__shfl_xor((int)p2, 32);
          unsigned e3 = (unsigned)__shfl_xor((int)p3, 32);
          bw[kt2][a][0] = hi ? e2 : p0;
          bw[kt2][a][1] = hi ? e3 : p1;
          bw[kt2][a][2] = hi ? p2 : e0;
          bw[kt2][a][3] = hi ? p3 : e1;
        }
      // O^T += V^T * P^T
#pragma unroll
      for (int db = 0; db < 2; ++db) {
        f32x16 acc = oacc[db];
        int rd = db * 32 + l31;
#pragma unroll
        for (int kt2 = 0; kt2 < 2; ++kt2)
#pragma unroll
          for (int a = 0; a < 2; ++a) {
            int c = kt2 * 4 + a * 2 + hi;
            bf16x8 vf = *(const bf16x8*)&V_[rd * 64 + (c ^ (rd & 7)) * 8];
            union { unsigned u[4]; bf16x8 v; } pun;
            pun.u[0] = bw[kt2][a][0]; pun.u[1] = bw[kt2][a][1];
            pun.u[2] = bw[kt2][a][2]; pun.u[3] = bw[kt2][a][3];
            acc = __builtin_amdgcn_mfma_f32_32x32x16_bf16(vf, pun.v, acc, 0, 0, 0);
          }
        oacc[db] = acc;
      }
    }
    __syncthreads();
  }
  // epilogue: O[q][d] = O^T / l
  float inv = 1.f / l_run;
  int q = q0w + l31;
#pragma unroll
  for (int db = 0; db < 2; ++db)
#pragma unroll
    for (int r = 0; r < 16; r += 2) {
      int d = db * 32 + (r & 3) + 8 * (r >> 2) + 4 * hi;
      unsigned short lo_ = f2bf(oacc[db][r] * inv);
      unsigned short hi_ = f2bf(oacc[db][r + 1] * inv);
      unsigned u = (unsigned)lo_ | ((unsigned)hi_ << 16);
      *(unsigned*)(o + (size_t)q * OD + h * 64 + d) = u;
    }
}

extern "C" void kernel_launch(void* const* d_in, const int* in_sizes, int n_in,
                              void* d_out, int out_size, void* d_ws, size_t ws_size,
                              hipStream_t stream) {
  const float* x          = (const float*)d_in[0];
  const float* norm_scale = (const float*)d_in[1];
  const float* qkv_w      = (const float*)d_in[2];
  const float* qkv_b      = (const float*)d_in[3];
  const float* out_w      = (const float*)d_in[4];
  const float* out_b      = (const float*)d_in[5];
  float* out = (float*)d_out;

  char* ws = (char*)d_ws;
  size_t off = 0;
  auto alloc = [&](size_t bytes) {
    void* p = ws + off;
    off += (bytes + 255) & ~(size_t)255;
    return p;
  };
  unsigned short* t_bf = (unsigned short*)alloc((size_t)T_SEQ * HID * 2);
  unsigned short* wqkv = (unsigned short*)alloc((size_t)QKV_D * HID * 2);
  unsigned short* wout = (unsigned short*)alloc((size_t)HID * OD * 2);
  unsigned short* qkv  = (unsigned short*)alloc((size_t)T_SEQ * QKV_D * 2);
  unsigned short* obuf = (unsigned short*)alloc((size_t)T_SEQ * OD * 2);
  unsigned short* vtb  = (unsigned short*)alloc((size_t)8 * 64 * T_SEQ * 2);
  float* ct = (float*)alloc((size_t)T_SEQ * 32 * 4);
  float* st = (float*)alloc((size_t)T_SEQ * 32 * 4);

  rmsnorm_k<<<dim3(T_SEQ), dim3(256), 0, stream>>>(x, norm_scale, t_bf);
  f2bf_k<<<dim3(1024), dim3(256), 0, stream>>>(qkv_w, wqkv, QKV_D * HID / 4);
  f2bf_k<<<dim3(1024), dim3(256), 0, stream>>>(out_w, wout, HID * OD / 4);
  rope_tab_k<<<dim3(T_SEQ * 32 / 256), dim3(256), 0, stream>>>(ct, st);
  gemm_k<false><<<dim3(QKV_D / 128, T_SEQ / 128), dim3(256), 0, stream>>>(
      t_bf, wqkv, qkv_b, nullptr, qkv, nullptr, T_SEQ, QKV_D, HID);
  rope_apply_k<<<dim3(T_SEQ * 72 * 32 / 256), dim3(256), 0, stream>>>(qkv, ct, st);
  vtrans_k<<<dim3(T_SEQ / 64, 8), dim3(256), 0, stream>>>(qkv, vtb);
  attn2_k<<<dim3(NQH, T_SEQ / 128), dim3(256), 0, stream>>>(qkv, vtb, obuf);
  gemm_k<true><<<dim3((HID + 127) / 128, T_SEQ / 128), dim3(256), 0, stream>>>(
      obuf, wout, out_b, x, nullptr, out, T_SEQ, HID, OD);
}

// Round 4
// 426.782 us; speedup vs baseline: 1.4148x; 1.0682x over previous
//
#include <hip/hip_runtime.h>
#include <stdint.h>
#include <math.h>

#define T_SEQ 2048
#define HID   2880
#define QKV_D 5120   // 64*80
#define OD    4096   // 64 heads * 64
#define NQH   64
#define SM_SCALE 0.125f
#define LOG2E 1.44269504088896340736f
#define SSL (SM_SCALE * LOG2E)

typedef float f32x4 __attribute__((ext_vector_type(4)));
typedef float f32x16 __attribute__((ext_vector_type(16)));
typedef short bf16x8 __attribute__((ext_vector_type(8)));

__device__ __forceinline__ unsigned short f2bf(float f) {
  union { float f; unsigned u; } v; v.f = f;
  unsigned r = v.u + 0x7fffu + ((v.u >> 16) & 1u);
  return (unsigned short)(r >> 16);
}
__device__ __forceinline__ float bf2f(unsigned short h) {
  union { unsigned u; float f; } v; v.u = ((unsigned)h) << 16;
  return v.f;
}
__device__ __forceinline__ void gld_lds16(const void* g, void* l) {
  __builtin_amdgcn_global_load_lds(
      (const __attribute__((address_space(1))) unsigned int*)g,
      (__attribute__((address_space(3))) unsigned int*)l, 16, 0, 0);
}

// ---------------- RMSNorm: x (f32) -> t (bf16) ----------------
__global__ __launch_bounds__(256) void rmsnorm_k(const float* __restrict__ x,
                                                 const float* __restrict__ scale,
                                                 unsigned short* __restrict__ t) {
  int row = blockIdx.x;
  const float4* xr = (const float4*)(x + (size_t)row * HID); // 720 float4
  float s = 0.f;
  for (int i = threadIdx.x; i < 720; i += 256) {
    float4 a = xr[i];
    s += a.x * a.x + a.y * a.y + a.z * a.z + a.w * a.w;
  }
#pragma unroll
  for (int off = 32; off; off >>= 1) s += __shfl_down(s, off);
  __shared__ float wsum[4];
  int w = threadIdx.x >> 6, lane = threadIdx.x & 63;
  if (lane == 0) wsum[w] = s;
  __syncthreads();
  float tot = wsum[0] + wsum[1] + wsum[2] + wsum[3];
  float r = rsqrtf(tot / (float)HID + 1e-5f);
  const float4* sc4 = (const float4*)scale;
  ushort4* tr = (ushort4*)(t + (size_t)row * HID);
  for (int i = threadIdx.x; i < 720; i += 256) {
    float4 a = xr[i]; float4 b = sc4[i];
    ushort4 o;
    o.x = f2bf(a.x * r * b.x); o.y = f2bf(a.y * r * b.y);
    o.z = f2bf(a.z * r * b.z); o.w = f2bf(a.w * r * b.w);
    tr[i] = o;
  }
}

// ---------------- f32 -> bf16 convert ----------------
__global__ __launch_bounds__(256) void f2bf_k(const float* __restrict__ in,
                                              unsigned short* __restrict__ out, int n4) {
  int i = blockIdx.x * 256 + threadIdx.x;
  int stride = gridDim.x * 256;
  for (; i < n4; i += stride) {
    float4 a = ((const float4*)in)[i];
    ushort4 o;
    o.x = f2bf(a.x); o.y = f2bf(a.y); o.z = f2bf(a.z); o.w = f2bf(a.w);
    ((ushort4*)out)[i] = o;
  }
}

// ---------------- RoPE cos/sin table (YaRN-style NTK) ----------------
__global__ __launch_bounds__(256) void rope_tab_k(float* __restrict__ ct, float* __restrict__ st) {
  int idx = blockIdx.x * 256 + threadIdx.x; // T_SEQ*32
  int i = idx & 31, t = idx >> 5;
  double fi = (double)i;
  double freq = pow(150000.0, fi / 32.0);
  double lb = log(150000.0);
  double low  = 32.0 * log(4096.0 / (32.0 * 2.0 * M_PI)) / lb;
  double high = 32.0 * log(4096.0 / (1.0  * 2.0 * M_PI)) / lb;
  double interp = 1.0 / (32.0 * freq);
  double extrap = 1.0 / freq;
  double ramp = (fi - low) / (high - low);
  ramp = fmin(fmax(ramp, 0.0), 1.0);
  double mask = 1.0 - ramp;
  double invf = interp * (1.0 - mask) + extrap * mask;
  double conc = 0.1 * log(32.0) + 1.0;
  double th = (double)t * invf;
  ct[idx] = (float)(cos(th) * conc);
  st[idx] = (float)(sin(th) * conc);
}

// ---------------- RoPE apply to q,k (bf16 in-place) ----------------
__global__ __launch_bounds__(256) void rope_apply_k(unsigned short* __restrict__ qkv,
                                                    const float* __restrict__ ct,
                                                    const float* __restrict__ st) {
  int idx = blockIdx.x * 256 + threadIdx.x; // T_SEQ*72*32
  int i = idx & 31;
  int hh = (idx >> 5) % 72;
  int t = idx / (72 * 32);
  size_t base = (size_t)t * QKV_D + hh * 64 + i;
  float x1 = bf2f(qkv[base]), x2 = bf2f(qkv[base + 32]);
  float c = ct[t * 32 + i], s = st[t * 32 + i];
  qkv[base]      = f2bf(x1 * c - x2 * s);
  qkv[base + 32] = f2bf(x2 * c + x1 * s);
}

// ---------------- V transpose: vt[kvh][d][t] = V[t][kvh][d] ----------------
__global__ __launch_bounds__(256) void vtrans_k(const unsigned short* __restrict__ qkv,
                                                unsigned short* __restrict__ vt) {
  __shared__ unsigned short tile[64][72];
  int g = blockIdx.y;
  int t0 = blockIdx.x * 64;
  int tid = threadIdx.x;
#pragma unroll
  for (int p = 0; p < 2; ++p) {
    int ch = p * 256 + tid;
    int i = ch >> 3, j0 = (ch & 7) * 8;
    bf16x8 v = *(const bf16x8*)(qkv + (size_t)(t0 + i) * QKV_D + 4608 + g * 64 + j0);
    *(bf16x8*)&tile[i][j0] = v;
  }
  __syncthreads();
#pragma unroll
  for (int p = 0; p < 2; ++p) {
    int ch = p * 256 + tid;
    int j = ch >> 3, i0 = (ch & 7) * 8;
    union { unsigned short u[8]; bf16x8 v; } pk;
#pragma unroll
    for (int m = 0; m < 8; ++m) pk.u[m] = tile[i0 + m][j];
    *(bf16x8*)(vt + (size_t)(g * 64 + j) * T_SEQ + t0 + i0) = pk.v;
  }
}

// ---- GEMM v2: 128x128 tile, 8 waves, dbuf LDS + STAGE-ahead, XCD swizzle ----
// C[M][N] = A[M][K] * B[N][K]^T (+bias)(+resid). Requires K%32==0, M%128==0,
// grid (ceil(N/128), M/128) with nwg%8==0.
template <bool FINAL>
__global__ __launch_bounds__(512, 4) void gemm8_k(const unsigned short* __restrict__ A,
                                                  const unsigned short* __restrict__ B,
                                                  const float* __restrict__ bias,
                                                  const float* __restrict__ resid,
                                                  unsigned short* __restrict__ Cb,
                                                  float* __restrict__ Cf,
                                                  int M, int N, int K) {
  __shared__ unsigned short As[2][128 * 32];
  __shared__ unsigned short Bs[2][128 * 32];
  int tid = threadIdx.x;
  int w = tid >> 6, lane = tid & 63;
  int g = lane >> 4, ln = lane & 15;
  // XCD-aware bijective swizzle (nwg % 8 == 0)
  int nwg = gridDim.x * gridDim.y;
  int lin = blockIdx.y * gridDim.x + blockIdx.x;
  int swz = (lin & 7) * (nwg >> 3) + (lin >> 3);
  int bx = swz % gridDim.x, by = swz / gridDim.x;
  int m0 = by * 128, n0 = bx * 128;
  int wr = w >> 1, wc = w & 1;  // 4x2 wave grid: 32 rows x 64 cols per wave
  f32x4 acc[2][4];
#pragma unroll
  for (int a = 0; a < 2; a++)
#pragma unroll
    for (int b = 0; b < 4; b++) acc[a][b] = (f32x4){0.f, 0.f, 0.f, 0.f};

  // staging: 512 chunks of 16B per matrix, one per thread
  int srow = tid >> 2, scc = tid & 3;
  int sg = scc ^ (srow & 3);
  const unsigned short* gA = A + (size_t)(m0 + srow) * K + sg * 8;
  int rowB = n0 + srow; if (rowB > N - 1) rowB = N - 1;
  const unsigned short* gB = B + (size_t)rowB * K + sg * 8;

  int nt = K >> 5;
  // prologue
  gld_lds16(gA, &As[0][(w * 64) * 8]);
  gld_lds16(gB, &Bs[0][(w * 64) * 8]);
  __syncthreads();
  int cur = 0;
  for (int t = 0; t < nt; ++t) {
    if (t + 1 < nt) {
      int k0 = (t + 1) << 5;
      gld_lds16(gA + k0, &As[cur ^ 1][(w * 64) * 8]);
      gld_lds16(gB + k0, &Bs[cur ^ 1][(w * 64) * 8]);
    }
    bf16x8 af[2], bfr[4];
#pragma unroll
    for (int mi = 0; mi < 2; ++mi) {
      int rm = wr * 32 + mi * 16 + ln;
      int c = g ^ (rm & 3);
      af[mi] = *(const bf16x8*)&As[cur][rm * 32 + c * 8];
    }
#pragma unroll
    for (int ni = 0; ni < 4; ++ni) {
      int rn = wc * 64 + ni * 16 + ln;
      int c = g ^ (rn & 3);
      bfr[ni] = *(const bf16x8*)&Bs[cur][rn * 32 + c * 8];
    }
#pragma unroll
    for (int mi = 0; mi < 2; ++mi)
#pragma unroll
      for (int ni = 0; ni < 4; ++ni)
        acc[mi][ni] = __builtin_amdgcn_mfma_f32_16x16x32_bf16(af[mi], bfr[ni], acc[mi][ni], 0, 0, 0);
    __syncthreads();
    cur ^= 1;
  }
#pragma unroll
  for (int mi = 0; mi < 2; ++mi)
#pragma unroll
    for (int ni = 0; ni < 4; ++ni) {
      int colB = n0 + wc * 64 + ni * 16 + ln;
      if (colB >= N) continue;
      float bv = bias[colB];
#pragma unroll
      for (int r = 0; r < 4; ++r) {
        int rowC = m0 + wr * 32 + mi * 16 + g * 4 + r;
        float v = acc[mi][ni][r] + bv;
        if (FINAL) {
          Cf[(size_t)rowC * N + colB] = v + resid[(size_t)rowC * N + colB];
        } else {
          Cb[(size_t)rowC * N + colB] = f2bf(v);
        }
      }
    }
}

// ---------------- Flash attention v2b: 32x32 swapped-operand, causal GQA ----------------
__global__ __launch_bounds__(256) void attn2_k(const unsigned short* __restrict__ qkv,
                                               const unsigned short* __restrict__ vt,
                                               unsigned short* __restrict__ o) {
  __shared__ unsigned short Ks[2][64 * 64];
  __shared__ unsigned short Vs[2][64 * 64];
  int h = blockIdx.x;
  int qt = (int)gridDim.y - 1 - (int)blockIdx.y;  // long blocks first
  int tid = threadIdx.x;
  int w = tid >> 6, lane = tid & 63;
  int l31 = lane & 31, hi = lane >> 5;
  int qb0 = qt * 128;
  int q0w = qb0 + w * 32;
  int kvh = h >> 3;
  const unsigned short* kbase = qkv + 4096 + (size_t)kvh * 64;
  const unsigned short* vtb = vt + (size_t)kvh * 64 * T_SEQ;

  bf16x8 qf[4];
  {
    const unsigned short* qrow = qkv + (size_t)(q0w + l31) * QKV_D + h * 64;
#pragma unroll
    for (int dt = 0; dt < 4; ++dt)
      qf[dt] = *(const bf16x8*)(qrow + dt * 16 + hi * 8);
  }
  f32x16 oacc[2];
#pragma unroll
  for (int r = 0; r < 16; ++r) { oacc[0][r] = 0.f; oacc[1][r] = 0.f; }
  float m_run = -1e30f, l_run = 0.f;
  int nt = qt * 2 + 2;

  auto STAGE = [&](int t, int buf) {
    int kv0 = t * 64;
#pragma unroll
    for (int p = 0; p < 2; ++p) {
      int ch = p * 256 + w * 64 + lane;
      int row = ch >> 3, cc = ch & 7;
      int gch = cc ^ (row & 7);
      gld_lds16(kbase + (size_t)(kv0 + row) * QKV_D + gch * 8, &Ks[buf][(p * 256 + w * 64) * 8]);
      gld_lds16(vtb + (size_t)row * T_SEQ + kv0 + gch * 8, &Vs[buf][(p * 256 + w * 64) * 8]);
    }
  };

  STAGE(0, 0);
  __syncthreads();
  for (int t = 0; t < nt; ++t) {
    int cur = t & 1;
    if (t + 1 < nt) STAGE(t + 1, cur ^ 1);
    int kv0 = t * 64;
    if (kv0 <= q0w + 31) {
      const unsigned short* K_ = Ks[cur];
      const unsigned short* V_ = Vs[cur];
      f32x16 pa[2];
#pragma unroll
      for (int kt2 = 0; kt2 < 2; ++kt2) {
        f32x16 acc;
#pragma unroll
        for (int r = 0; r < 16; ++r) acc[r] = 0.f;
        int rk = kt2 * 32 + l31;
#pragma unroll
        for (int dt = 0; dt < 4; ++dt) {
          int c = dt * 2 + hi;
          bf16x8 kf = *(const bf16x8*)&K_[rk * 64 + (c ^ (rk & 7)) * 8];
          acc = __builtin_amdgcn_mfma_f32_32x32x16_bf16(kf, qf[dt], acc, 0, 0, 0);
        }
        pa[kt2] = acc;
      }
      bool diag = (kv0 + 64 > q0w);
      int q = q0w + l31;
      float s2[32];
#pragma unroll
      for (int kt2 = 0; kt2 < 2; ++kt2)
#pragma unroll
        for (int r = 0; r < 16; ++r) {
          float x = pa[kt2][r] * SSL;
          if (diag) {
            int k = kv0 + kt2 * 32 + (r & 3) + 8 * (r >> 2) + 4 * hi;
            if (k > q) x = -3.0e38f;
          }
          s2[kt2 * 16 + r] = x;
        }
      float mx = s2[0];
#pragma unroll
      for (int i = 1; i < 32; ++i) mx = fmaxf(mx, s2[i]);
      mx = fmaxf(mx, __shfl_xor(mx, 32));
      float mnew = fmaxf(m_run, mx);
      float alpha = exp2f(m_run - mnew);
      m_run = mnew;
      float sum = 0.f;
#pragma unroll
      for (int i = 0; i < 32; ++i) {
        float p = exp2f(s2[i] - mnew);
        s2[i] = p;
        sum += p;
      }
      sum += __shfl_xor(sum, 32);
      l_run = l_run * alpha + sum;
#pragma unroll
      for (int r = 0; r < 16; ++r) { oacc[0][r] *= alpha; oacc[1][r] *= alpha; }
      unsigned pw[16];
#pragma unroll
      for (int kt2 = 0; kt2 < 2; ++kt2)
#pragma unroll
        for (int i = 0; i < 8; ++i) {
          unsigned r_;
          asm("v_cvt_pk_bf16_f32 %0, %1, %2"
              : "=v"(r_) : "v"(s2[kt2 * 16 + 2 * i]), "v"(s2[kt2 * 16 + 2 * i + 1]));
          pw[kt2 * 8 + i] = r_;
        }
      unsigned bw[2][2][4];
#pragma unroll
      for (int kt2 = 0; kt2 < 2; ++kt2)
#pragma unroll
        for (int a = 0; a < 2; ++a) {
          unsigned p0 = pw[kt2 * 8 + a * 4 + 0];
          unsigned p1 = pw[kt2 * 8 + a * 4 + 1];
          unsigned p2 = pw[kt2 * 8 + a * 4 + 2];
          unsigned p3 = pw[kt2 * 8 + a * 4 + 3];
          unsigned e0 = (unsigned)__shfl_xor((int)p0, 32);
          unsigned e1 = (unsigned)__shfl_xor((int)p1, 32);
          unsigned e2 = (unsigned)__shfl_xor((int)p2, 32);
          unsigned e3 = (unsigned)__shfl_xor((int)p3, 32);
          bw[kt2][a][0] = hi ? e2 : p0;
          bw[kt2][a][1] = hi ? e3 : p1;
          bw[kt2][a][2] = hi ? p2 : e0;
          bw[kt2][a][3] = hi ? p3 : e1;
        }
#pragma unroll
      for (int db = 0; db < 2; ++db) {
        f32x16 acc = oacc[db];
        int rd = db * 32 + l31;
#pragma unroll
        for (int kt2 = 0; kt2 < 2; ++kt2)
#pragma unroll
          for (int a = 0; a < 2; ++a) {
            int c = kt2 * 4 + a * 2 + hi;
            bf16x8 vf = *(const bf16x8*)&V_[rd * 64 + (c ^ (rd & 7)) * 8];
            union { unsigned u[4]; bf16x8 v; } pun;
            pun.u[0] = bw[kt2][a][0]; pun.u[1] = bw[kt2][a][1];
            pun.u[2] = bw[kt2][a][2]; pun.u[3] = bw[kt2][a][3];
            acc = __builtin_amdgcn_mfma_f32_32x32x16_bf16(vf, pun.v, acc, 0, 0, 0);
          }
        oacc[db] = acc;
      }
    }
    __syncthreads();
  }
  float inv = 1.f / l_run;
  int q = q0w + l31;
#pragma unroll
  for (int db = 0; db < 2; ++db)
#pragma unroll
    for (int r = 0; r < 16; r += 2) {
      int d = db * 32 + (r & 3) + 8 * (r >> 2) + 4 * hi;
      unsigned short lo_ = f2bf(oacc[db][r] * inv);
      unsigned short hi_ = f2bf(oacc[db][r + 1] * inv);
      unsigned u = (unsigned)lo_ | ((unsigned)hi_ << 16);
      *(unsigned*)(o + (size_t)q * OD + h * 64 + d) = u;
    }
}

extern "C" void kernel_launch(void* const* d_in, const int* in_sizes, int n_in,
                              void* d_out, int out_size, void* d_ws, size_t ws_size,
                              hipStream_t stream) {
  const float* x          = (const float*)d_in[0];
  const float* norm_scale = (const float*)d_in[1];
  const float* qkv_w      = (const float*)d_in[2];
  const float* qkv_b      = (const float*)d_in[3];
  const float* out_w      = (const float*)d_in[4];
  const float* out_b      = (const float*)d_in[5];
  float* out = (float*)d_out;

  char* ws = (char*)d_ws;
  size_t off = 0;
  auto alloc = [&](size_t bytes) {
    void* p = ws + off;
    off += (bytes + 255) & ~(size_t)255;
    return p;
  };
  unsigned short* t_bf = (unsigned short*)alloc((size_t)T_SEQ * HID * 2);
  unsigned short* wqkv = (unsigned short*)alloc((size_t)QKV_D * HID * 2);
  unsigned short* wout = (unsigned short*)alloc((size_t)HID * OD * 2);
  unsigned short* qkv  = (unsigned short*)alloc((size_t)T_SEQ * QKV_D * 2);
  unsigned short* obuf = (unsigned short*)alloc((size_t)T_SEQ * OD * 2);
  unsigned short* vtb  = (unsigned short*)alloc((size_t)8 * 64 * T_SEQ * 2);
  float* ct = (float*)alloc((size_t)T_SEQ * 32 * 4);
  float* st = (float*)alloc((size_t)T_SEQ * 32 * 4);

  rmsnorm_k<<<dim3(T_SEQ), dim3(256), 0, stream>>>(x, norm_scale, t_bf);
  f2bf_k<<<dim3(1024), dim3(256), 0, stream>>>(qkv_w, wqkv, QKV_D * HID / 4);
  f2bf_k<<<dim3(1024), dim3(256), 0, stream>>>(out_w, wout, HID * OD / 4);
  rope_tab_k<<<dim3(T_SEQ * 32 / 256), dim3(256), 0, stream>>>(ct, st);
  gemm8_k<false><<<dim3(QKV_D / 128, T_SEQ / 128), dim3(512), 0, stream>>>(
      t_bf, wqkv, qkv_b, nullptr, qkv, nullptr, T_SEQ, QKV_D, HID);
  rope_apply_k<<<dim3(T_SEQ * 72 * 32 / 256), dim3(256), 0, stream>>>(qkv, ct, st);
  vtrans_k<<<dim3(T_SEQ / 64, 8), dim3(256), 0, stream>>>(qkv, vtb);
  attn2_k<<<dim3(NQH, T_SEQ / 128), dim3(256), 0, stream>>>(qkv, vtb, obuf);
  gemm8_k<true><<<dim3((HID + 127) / 128, T_SEQ / 128), dim3(512), 0, stream>>>(
      obuf, wout, out_b, x, nullptr, out, T_SEQ, HID, OD);
}